// Round 7
// baseline (709.221 us; speedup 1.0000x reference)
//
#include <hip/hip_runtime.h>
#include <math.h>

#define NN 4096
#define NE 16384
#define NG 64

// ---- ws layout (float offsets); zero region first (~51KB memset) ----
#define OFF_DEG   0         // 4096
#define OFF_ST1   4096      // 64
#define OFF_ST2   4160      // 128
#define OFF_ST3   4288      // 256
#define OFF_POOL  4544      // 64*128 = 8192
#define OFF_CNT   12736     // 16 ints (gate counters: 0,1,2 = egst1..3, 3 = pool)
#define ZERO_FLOATS 12752
#define OFF_H1    12752     // 4096*32
#define OFF_H2    143824    // 4096*64
#define OFF_H3    405968    // 4096*128
#define OFF_Y     930256    // 4096*1152 max (reused across layers)

// ---------------- gate helpers (device-coherent counter, no L2 writeback needed:
// producers' payload writes are device-scope atomics) ----------------
__device__ __forceinline__ void gate_post(int* cnt) {
    // every wave drains its own outstanding VMEM (atomics) before the release
    asm volatile("s_waitcnt vmcnt(0)" ::: "memory");
    __syncthreads();
    if (threadIdx.x == 0)
        __hip_atomic_fetch_add(cnt, 1, __ATOMIC_RELEASE, __HIP_MEMORY_SCOPE_AGENT);
}
__device__ __forceinline__ void gate_wait(int* cnt, int target) {
    if (threadIdx.x == 0) {
        while (__hip_atomic_load(cnt, __ATOMIC_RELAXED, __HIP_MEMORY_SCOPE_AGENT) < target)
            __builtin_amdgcn_s_sleep(8);
        (void)__hip_atomic_load(cnt, __ATOMIC_ACQUIRE, __HIP_MEMORY_SCOPE_AGENT); // cache-inv
    }
    __syncthreads();
}

// ---------------- proj: Y[n,col]=sum_i bnp(A[n,i])*Bcat[i,col]; resid cols -> h-init ----------------
// Bcat built on the fly from We/be/Wr:
//   col = f*COUT + o;  f<8 -> We[f*K*COUT + o*K + i];  f==8 -> be[o*K+i];  f==9 -> Wr[i*COUT+o]
// cols < 9*COUT -> Y (unnormalized; norm applied in egather)
// cols >= 9*COUT -> h[m*COUT+o] = acc + bias[o] + br[o]   (residual init, written once)
// DEG=true: trailing 64 blocks count src out-degree (independent work, merged launch).
template<int K, int COUT, bool BN, bool DEG>
__global__ __launch_bounds__(256) void k_proj(
    const float* __restrict__ A,
    const float* __restrict__ We, const float* __restrict__ be,
    const float* __restrict__ Wr, const float* __restrict__ bias,
    const float* __restrict__ br,
    const int* __restrict__ ei, float* __restrict__ deg,
    float* __restrict__ Y, float* __restrict__ h,
    const float* __restrict__ st, const float* __restrict__ g,
    const float* __restrict__ b, const float* __restrict__ a)
{
    constexpr int NCOL = 10 * COUT;
    constexpr int NY = NCOL / 64;       // exact: 5 / 10 / 20
    constexpr int NC9 = 9 * COUT;
    constexpr int L2C = (COUT == 32) ? 5 : (COUT == 64) ? 6 : 7;

    const int tid = threadIdx.x;
    const int bid = blockIdx.x;

    if constexpr (DEG) {
        if (bid >= 64 * NY) {
            int e = (bid - 64 * NY) * 256 + tid;
            if (e < NE) atomicAdd(&deg[ei[e]], 1.0f);
            return;
        }
    }

    __shared__ float sA[K][68];
    __shared__ float sB[K][68];
    __shared__ float sS[K];
    __shared__ float sT[K];
    const int m0 = (bid & 63) * 64;
    const int n0 = (bid >> 6) * 64;

    float al = 0.f;
    if constexpr (BN) {
        if (tid < K) {
            float mean = st[tid] * (1.f / NN);
            float var  = st[K + tid] * (1.f / NN) - mean * mean;
            var = fmaxf(var, 0.f);
            float s = rsqrtf(var + 1e-5f) * g[tid];
            sS[tid] = s;
            sT[tid] = b[tid] - mean * s;
        }
        al = a[0];
        __syncthreads();
    }

    for (int t = tid; t < 64 * K; t += 256) {
        int m = t / K, i = t - m * K;
        float v = A[(m0 + m) * K + i];
        if constexpr (BN) {
            v = fmaf(v, sS[i], sT[i]);
            v = v >= 0.f ? v : al * v;
        }
        sA[i][m] = v;
    }
    for (int t = tid; t < 64 * K; t += 256) {
        int i = t >> 6, n = t & 63;
        int col = n0 + n;
        int f = col >> L2C;
        int o = col & (COUT - 1);
        float v;
        if (f < 8)       v = We[f * K * COUT + o * K + i];
        else if (f == 8) v = be[o * K + i];
        else             v = Wr[i * COUT + o];
        sB[i][n] = v;
    }
    __syncthreads();

    const int tn = tid & 15, tm = tid >> 4;
    float acc[4][4] = {{0.f}};
#pragma unroll 8
    for (int i = 0; i < K; ++i) {
        float4 av = *(const float4*)&sA[i][tm * 4];
        float4 bv = *(const float4*)&sB[i][tn * 4];
        acc[0][0] += av.x * bv.x; acc[0][1] += av.x * bv.y; acc[0][2] += av.x * bv.z; acc[0][3] += av.x * bv.w;
        acc[1][0] += av.y * bv.x; acc[1][1] += av.y * bv.y; acc[1][2] += av.y * bv.z; acc[1][3] += av.y * bv.w;
        acc[2][0] += av.z * bv.x; acc[2][1] += av.z * bv.y; acc[2][2] += av.z * bv.z; acc[2][3] += av.z * bv.w;
        acc[3][0] += av.w * bv.x; acc[3][1] += av.w * bv.y; acc[3][2] += av.w * bv.z; acc[3][3] += av.w * bv.w;
    }

#pragma unroll
    for (int mm = 0; mm < 4; ++mm) {
        int m = m0 + tm * 4 + mm;
#pragma unroll
        for (int nn = 0; nn < 4; ++nn) {
            int col = n0 + tn * 4 + nn;
            if (col < NC9) {
                Y[(size_t)m * NC9 + col] = acc[mm][nn];
            } else {
                int o = col - NC9;
                h[m * COUT + o] = acc[mm][nn] + bias[o] + br[o];
            }
        }
    }
}

// ---------------- egstats: eg blocks (atomic scatter into h) + 256 tail stats blocks
// gated on a device counter (producers' h-writes are atomics -> already coherent) ----------------
template<int COUT, int NEGB>
__global__ __launch_bounds__(256) void k_egstats(
    const float* __restrict__ Y, const float* __restrict__ eattr,
    const int* __restrict__ ei, const float* __restrict__ deg,
    float* __restrict__ h, float* __restrict__ st, int* __restrict__ cnt)
{
    const int tid = threadIdx.x;
    const int bid = blockIdx.x;
    __shared__ float sred[256];

    if (bid < NEGB) {
        int idx = bid * 256 + tid;
        int e = idx / COUT;
        int o = idx - e * COUT;
        int src = ei[e], dst = ei[NE + e];
        float d = deg[src];
        float nrm = d > 0.f ? 1.f / d : 0.f;
        const float* y = Y + (size_t)src * (9 * COUT);
        const float* ea = eattr + e * 8;
        float acc = y[8 * COUT + o];      // be-term, ea' = 1
#pragma unroll
        for (int f = 0; f < 8; ++f) acc += ea[f] * y[f * COUT + o];
        atomicAdd(&h[dst * COUT + o], nrm * acc);
        gate_post(cnt);
        return;
    }

    // ---- stats tail: wait for all eg blocks, then per-channel sum/sumsq ----
    gate_wait(cnt, NEGB);
    constexpr int NL = 256 / COUT;
    constexpr int KN = 16 / NL;
    const int nbase = (bid - NEGB) * 16;
    const int o = tid % COUT;
    const int nl = tid / COUT;

    float sum = 0.f, sumsq = 0.f;
#pragma unroll
    for (int k = 0; k < KN; ++k) {
        int r = nl * KN + k;
        float v = h[(nbase + r) * COUT + o];
        sum += v; sumsq += v * v;
    }
    sred[tid] = sum;
    __syncthreads();
    if (tid < COUT) {
        float s = 0.f;
        for (int q = 0; q < NL; ++q) s += sred[q * COUT + tid];
        atomicAdd(&st[tid], s);
    }
    __syncthreads();
    sred[tid] = sumsq;
    __syncthreads();
    if (tid < COUT) {
        float s = 0.f;
        for (int q = 0; q < NL; ++q) s += sred[q * COUT + tid];
        atomicAdd(&st[COUT + tid], s);
    }
}

// ---------------- poolfinal: 256 pool blocks (atomic scatter into pooled) + 64 tail final blocks ----------------
__global__ __launch_bounds__(256) void k_poolfinal(
    const float* __restrict__ h3, const int* __restrict__ batch,
    const float* __restrict__ Wi, const float* __restrict__ bi,
    const float* __restrict__ Wj, const float* __restrict__ bj,
    float* __restrict__ pooled,
    const float* __restrict__ st, const float* __restrict__ g,
    const float* __restrict__ b, const float* __restrict__ a,
    const float* __restrict__ Wfc, const float* __restrict__ bfc,
    float* __restrict__ out, int* __restrict__ cnt)
{
    constexpr int KN = 8, NB = 16;
    __shared__ float sH[NB * 128];
    __shared__ int sB[NB];
    __shared__ float sS[128];
    __shared__ float sT[128];
    const int tid = threadIdx.x;
    const int bid = blockIdx.x;

    if (bid < 256) {
        const int nbase = bid * NB;
        if (tid < 128) {
            float mean = st[tid] * (1.f / NN);
            float var  = st[128 + tid] * (1.f / NN) - mean * mean;
            var = fmaxf(var, 0.f);
            float s = rsqrtf(var + 1e-5f) * g[tid];
            sS[tid] = s;
            sT[tid] = b[tid] - mean * s;
        }
        if (tid < NB) sB[tid] = batch[nbase + tid];
        __syncthreads();
        const float al = a[0];

        for (int t = tid; t < NB * 128; t += 256) {
            int c = t & 127;
            float v = h3[nbase * 128 + t];
            v = fmaf(v, sS[c], sT[c]);
            v = v >= 0.f ? v : al * v;
            sH[t] = v;
        }
        __syncthreads();

        const int o = tid & 127, nl = tid >> 7;
        float gacc[KN], facc[KN];
#pragma unroll
        for (int k = 0; k < KN; ++k) { gacc[k] = 0.f; facc[k] = 0.f; }
        for (int i = 0; i < 128; ++i) {
            float wi = Wi[i * 128 + o], wj = Wj[i * 128 + o];
#pragma unroll
            for (int k = 0; k < KN; ++k) {
                float hv = sH[(nl * KN + k) * 128 + i];
                gacc[k] += hv * wi;
                facc[k] += hv * wj;
            }
        }
        float bio = bi[o], bjo = bj[o];
        float psum = 0.f;
        int curg = sB[nl * KN];
#pragma unroll
        for (int k = 0; k < KN; ++k) {
            int r = nl * KN + k;
            int bg = sB[r];
            if (bg != curg) {
                atomicAdd(&pooled[curg * 128 + o], psum);
                psum = 0.f; curg = bg;
            }
            float gate = 1.f / (1.f + expf(-(gacc[k] + bio)));
            float feat = tanhf(facc[k] + bjo);
            psum += gate * feat;
        }
        atomicAdd(&pooled[curg * 128 + o], psum);
        gate_post(cnt);
        return;
    }

    // ---- final tail: tanh(pooled) @ Wfc + bfc, split halves ----
    gate_wait(cnt, 256);
    float* sP = sS;   // reuse
    const int gid = bid - 256;
    if (tid < 128) sP[tid] = tanhf(pooled[gid * 128 + tid]);
    __syncthreads();
    float z = bfc[tid];
    for (int i = 0; i < 128; ++i) z += sP[i] * Wfc[i * 256 + tid];
    int oidx = (tid < 128) ? (gid * 128 + tid) : (NG * 128 + gid * 128 + (tid - 128));
    out[oidx] = z;
}

extern "C" void kernel_launch(void* const* d_in, const int* in_sizes, int n_in,
                              void* d_out, int out_size, void* d_ws, size_t ws_size,
                              hipStream_t stream)
{
    (void)in_sizes; (void)n_in; (void)out_size; (void)ws_size;
    const float* x     = (const float*)d_in[0];
    const float* eattr = (const float*)d_in[1];
    const int*   ei    = (const int*)d_in[2];
    const int*   batch = (const int*)d_in[3];
    const float* We1 = (const float*)d_in[4];
    const float* be1 = (const float*)d_in[5];
    const float* bias1 = (const float*)d_in[6];
    const float* Wr1 = (const float*)d_in[7];
    const float* br1 = (const float*)d_in[8];
    const float* bg1 = (const float*)d_in[9];
    const float* bb1 = (const float*)d_in[10];
    const float* a1  = (const float*)d_in[11];
    const float* We2 = (const float*)d_in[12];
    const float* be2 = (const float*)d_in[13];
    const float* bias2 = (const float*)d_in[14];
    const float* Wr2 = (const float*)d_in[15];
    const float* br2 = (const float*)d_in[16];
    const float* bg2 = (const float*)d_in[17];
    const float* bb2 = (const float*)d_in[18];
    const float* a2  = (const float*)d_in[19];
    const float* We3 = (const float*)d_in[20];
    const float* be3 = (const float*)d_in[21];
    const float* bias3 = (const float*)d_in[22];
    const float* Wr3 = (const float*)d_in[23];
    const float* br3 = (const float*)d_in[24];
    const float* bg3 = (const float*)d_in[25];
    const float* bb3 = (const float*)d_in[26];
    const float* a3  = (const float*)d_in[27];
    const float* Wi  = (const float*)d_in[28];
    const float* bi  = (const float*)d_in[29];
    const float* Wj  = (const float*)d_in[30];
    const float* bj  = (const float*)d_in[31];
    const float* Wfc = (const float*)d_in[32];
    const float* bfc = (const float*)d_in[33];
    float* ws  = (float*)d_ws;
    float* out = (float*)d_out;
    int* cnt = (int*)(ws + OFF_CNT);

    hipMemsetAsync(d_ws, 0, (size_t)ZERO_FLOATS * sizeof(float), stream);

    // layer 1: K=16, COUT=32 (no BN on x); deg-count blocks merged into proj1 launch
    k_proj<16, 32, false, true><<<64 * 5 + 64, 256, 0, stream>>>(
        x, We1, be1, Wr1, bias1, br1, ei, ws + OFF_DEG,
        ws + OFF_Y, ws + OFF_H1, nullptr, nullptr, nullptr, nullptr);
    k_egstats<32, NE * 32 / 256><<<NE * 32 / 256 + 256, 256, 0, stream>>>(
        ws + OFF_Y, eattr, ei, ws + OFF_DEG, ws + OFF_H1, ws + OFF_ST1, cnt + 0);

    // layer 2: K=32, COUT=64 (BN1 folded into A load)
    k_proj<32, 64, true, false><<<64 * 10, 256, 0, stream>>>(
        ws + OFF_H1, We2, be2, Wr2, bias2, br2, nullptr, nullptr,
        ws + OFF_Y, ws + OFF_H2, ws + OFF_ST1, bg1, bb1, a1);
    k_egstats<64, NE * 64 / 256><<<NE * 64 / 256 + 256, 256, 0, stream>>>(
        ws + OFF_Y, eattr, ei, ws + OFF_DEG, ws + OFF_H2, ws + OFF_ST2, cnt + 1);

    // layer 3: K=64, COUT=128 (BN2 folded)
    k_proj<64, 128, true, false><<<64 * 20, 256, 0, stream>>>(
        ws + OFF_H2, We3, be3, Wr3, bias3, br3, nullptr, nullptr,
        ws + OFF_Y, ws + OFF_H3, ws + OFF_ST2, bg2, bb2, a2);
    k_egstats<128, NE * 128 / 256><<<NE * 128 / 256 + 256, 256, 0, stream>>>(
        ws + OFF_Y, eattr, ei, ws + OFF_DEG, ws + OFF_H3, ws + OFF_ST3, cnt + 2);

    // pooling (BN3 folded, run-aggregated atomics) + head, gated in one launch
    k_poolfinal<<<256 + NG, 256, 0, stream>>>(
        ws + OFF_H3, batch, Wi, bi, Wj, bj, ws + OFF_POOL,
        ws + OFF_ST3, bg3, bb3, a3, Wfc, bfc, out, cnt + 3);
}

// Round 8
// 277.196 us; speedup vs baseline: 2.5586x; 2.5586x over previous
//
#include <hip/hip_runtime.h>
#include <math.h>

#define NN 4096
#define NE 16384
#define NG 64

// ---- ws layout (float offsets); zero region first (~51KB memset) ----
#define OFF_DEG   0         // 4096
#define OFF_ST1   4096      // 64
#define OFF_ST2   4160      // 128
#define OFF_ST3   4288      // 256
#define OFF_POOL  4544      // 64*128 = 8192
#define ZERO_FLOATS 12736
#define OFF_H1    12736     // 4096*32
#define OFF_H2    143808    // 4096*64
#define OFF_H3    405952    // 4096*128
#define OFF_Y     930240    // 4096*1152 max (reused across layers)

// ---------------- proj: Y[n,col]=sum_i bnp(A[n,i])*Bcat[i,col]; resid cols -> h-init ----------------
// Bcat built on the fly from We/be/Wr (no materialization):
//   col = f*COUT + o;  f<8 -> We[f*K*COUT + o*K + i];  f==8 -> be[o*K+i];  f==9 -> Wr[i*COUT+o]
// cols < 9*COUT -> Y (unnormalized; norm applied in egather)
// cols >= 9*COUT -> h[m*COUT+o] = acc + bias[o] + br[o]   (residual init, written once)
// DEG=true: trailing 64 blocks count src out-degree (independent work, merged launch).
// B-staging uses i-fast thread map: global reads coalesced (contiguous in i);
// the resulting 8-way LDS write conflict on sB is far cheaper than 64x uncoalesced global.
template<int K, int COUT, bool BN, bool DEG>
__global__ __launch_bounds__(256) void k_proj(
    const float* __restrict__ A,
    const float* __restrict__ We, const float* __restrict__ be,
    const float* __restrict__ Wr, const float* __restrict__ bias,
    const float* __restrict__ br,
    const int* __restrict__ ei, float* __restrict__ deg,
    float* __restrict__ Y, float* __restrict__ h,
    const float* __restrict__ st, const float* __restrict__ g,
    const float* __restrict__ b, const float* __restrict__ a)
{
    constexpr int NCOL = 10 * COUT;
    constexpr int NY = NCOL / 64;       // exact: 5 / 10 / 20
    constexpr int NC9 = 9 * COUT;
    constexpr int L2C = (COUT == 32) ? 5 : (COUT == 64) ? 6 : 7;

    const int tid = threadIdx.x;
    const int bid = blockIdx.x;

    if constexpr (DEG) {
        if (bid >= 64 * NY) {
            int e = (bid - 64 * NY) * 256 + tid;
            if (e < NE) atomicAdd(&deg[ei[e]], 1.0f);
            return;
        }
    }

    __shared__ float sA[K][68];
    __shared__ float sB[K][68];
    __shared__ float sS[K];
    __shared__ float sT[K];
    const int m0 = (bid & 63) * 64;
    const int n0 = (bid >> 6) * 64;

    float al = 0.f;
    if constexpr (BN) {
        if (tid < K) {
            float mean = st[tid] * (1.f / NN);
            float var  = st[K + tid] * (1.f / NN) - mean * mean;
            var = fmaxf(var, 0.f);
            float s = rsqrtf(var + 1e-5f) * g[tid];
            sS[tid] = s;
            sT[tid] = b[tid] - mean * s;
        }
        al = a[0];
        __syncthreads();
    }

    for (int t = tid; t < 64 * K; t += 256) {
        int m = t / K, i = t - m * K;      // i-fast: coalesced reads of A rows
        float v = A[(m0 + m) * K + i];
        if constexpr (BN) {
            v = fmaf(v, sS[i], sT[i]);
            v = v >= 0.f ? v : al * v;
        }
        sA[i][m] = v;
    }
    for (int t = tid; t < 64 * K; t += 256) {
        int n = t / K, i = t - n * K;      // i-fast: coalesced reads of We/be rows
        int col = n0 + n;
        int f = col >> L2C;
        int o = col & (COUT - 1);
        float v;
        if (f < 8)       v = We[f * K * COUT + o * K + i];
        else if (f == 8) v = be[o * K + i];
        else             v = Wr[i * COUT + o];
        sB[i][n] = v;
    }
    __syncthreads();

    const int tn = tid & 15, tm = tid >> 4;
    float acc[4][4] = {{0.f}};
#pragma unroll 8
    for (int i = 0; i < K; ++i) {
        float4 av = *(const float4*)&sA[i][tm * 4];
        float4 bv = *(const float4*)&sB[i][tn * 4];
        acc[0][0] += av.x * bv.x; acc[0][1] += av.x * bv.y; acc[0][2] += av.x * bv.z; acc[0][3] += av.x * bv.w;
        acc[1][0] += av.y * bv.x; acc[1][1] += av.y * bv.y; acc[1][2] += av.y * bv.z; acc[1][3] += av.y * bv.w;
        acc[2][0] += av.z * bv.x; acc[2][1] += av.z * bv.y; acc[2][2] += av.z * bv.z; acc[2][3] += av.z * bv.w;
        acc[3][0] += av.w * bv.x; acc[3][1] += av.w * bv.y; acc[3][2] += av.w * bv.z; acc[3][3] += av.w * bv.w;
    }

#pragma unroll
    for (int mm = 0; mm < 4; ++mm) {
        int m = m0 + tm * 4 + mm;
#pragma unroll
        for (int nn = 0; nn < 4; ++nn) {
            int col = n0 + tn * 4 + nn;
            if (col < NC9) {
                Y[(size_t)m * NC9 + col] = acc[mm][nn];
            } else {
                int o = col - NC9;
                h[m * COUT + o] = acc[mm][nn] + bias[o] + br[o];
            }
        }
    }
}

// ---------------- egather (float4): h[dst,4q..] += (1/deg[src]) * (sum_f ea[f]*Y4[src,f*TPE+q] + Y4[src,8*TPE+q]) ----------------
template<int COUT>
__global__ __launch_bounds__(256) void k_egather(
    const float* __restrict__ Y, const float* __restrict__ eattr,
    const int* __restrict__ ei, const float* __restrict__ deg,
    float* __restrict__ h)
{
    constexpr int TPE = COUT / 4;
    int idx = blockIdx.x * 256 + threadIdx.x;
    int e = idx / TPE;
    int q = idx - e * TPE;
    int src = ei[e], dst = ei[NE + e];
    float d = deg[src];
    float nrm = d > 0.f ? 1.f / d : 0.f;
    const float4* y4 = (const float4*)(Y + (size_t)src * (9 * COUT));
    const float4* ea4 = (const float4*)(eattr + e * 8);
    float4 ea0 = ea4[0], ea1 = ea4[1];
    float4 acc = y4[8 * TPE + q];     // be-term, ea' = 1
#define FMA4(s, v) { float4 _t = (v); acc.x += (s)*_t.x; acc.y += (s)*_t.y; acc.z += (s)*_t.z; acc.w += (s)*_t.w; }
    FMA4(ea0.x, y4[0 * TPE + q]);
    FMA4(ea0.y, y4[1 * TPE + q]);
    FMA4(ea0.z, y4[2 * TPE + q]);
    FMA4(ea0.w, y4[3 * TPE + q]);
    FMA4(ea1.x, y4[4 * TPE + q]);
    FMA4(ea1.y, y4[5 * TPE + q]);
    FMA4(ea1.z, y4[6 * TPE + q]);
    FMA4(ea1.w, y4[7 * TPE + q]);
#undef FMA4
    float* hp = h + (size_t)dst * COUT + 4 * q;
    atomicAdd(hp + 0, nrm * acc.x);
    atomicAdd(hp + 1, nrm * acc.y);
    atomicAdd(hp + 2, nrm * acc.z);
    atomicAdd(hp + 3, nrm * acc.w);
}

// ---------------- stats: per-channel sum/sumsq of h -> st ----------------
template<int COUT>
__global__ __launch_bounds__(256) void k_stats(
    const float* __restrict__ h, float* __restrict__ st)
{
    constexpr int NL = 256 / COUT;
    constexpr int KN = 16 / NL;
    __shared__ float sred[256];
    const int tid = threadIdx.x;
    const int nbase = blockIdx.x * 16;
    const int o = tid % COUT;
    const int nl = tid / COUT;

    float sum = 0.f, sumsq = 0.f;
#pragma unroll
    for (int k = 0; k < KN; ++k) {
        int r = nl * KN + k;
        float v = h[(nbase + r) * COUT + o];
        sum += v; sumsq += v * v;
    }
    sred[tid] = sum;
    __syncthreads();
    if (tid < COUT) {
        float s = 0.f;
        for (int q = 0; q < NL; ++q) s += sred[q * COUT + tid];
        atomicAdd(&st[tid], s);
    }
    __syncthreads();
    sred[tid] = sumsq;
    __syncthreads();
    if (tid < COUT) {
        float s = 0.f;
        for (int q = 0; q < NL; ++q) s += sred[q * COUT + tid];
        atomicAdd(&st[COUT + tid], s);
    }
}

// ---------------- pool: BN3+PReLU3 on load, gated attention, run-aggregated atomics ----------------
__global__ __launch_bounds__(256) void k_pool(
    const float* __restrict__ h3, const int* __restrict__ batch,
    const float* __restrict__ Wi, const float* __restrict__ bi,
    const float* __restrict__ Wj, const float* __restrict__ bj,
    float* __restrict__ pooled,
    const float* __restrict__ st, const float* __restrict__ g,
    const float* __restrict__ b, const float* __restrict__ a)
{
    constexpr int KN = 8, NB = 16;
    __shared__ float sH[NB * 128];
    __shared__ int sB[NB];
    __shared__ float sS[128];
    __shared__ float sT[128];
    const int tid = threadIdx.x;
    const int nbase = blockIdx.x * NB;

    if (tid < 128) {
        float mean = st[tid] * (1.f / NN);
        float var  = st[128 + tid] * (1.f / NN) - mean * mean;
        var = fmaxf(var, 0.f);
        float s = rsqrtf(var + 1e-5f) * g[tid];
        sS[tid] = s;
        sT[tid] = b[tid] - mean * s;
    }
    if (tid < NB) sB[tid] = batch[nbase + tid];
    __syncthreads();
    const float al = a[0];

    for (int t = tid; t < NB * 128; t += 256) {
        int c = t & 127;
        float v = h3[nbase * 128 + t];
        v = fmaf(v, sS[c], sT[c]);
        v = v >= 0.f ? v : al * v;
        sH[t] = v;
    }
    __syncthreads();

    const int o = tid & 127, nl = tid >> 7;
    float gacc[KN], facc[KN];
#pragma unroll
    for (int k = 0; k < KN; ++k) { gacc[k] = 0.f; facc[k] = 0.f; }
    for (int i = 0; i < 128; ++i) {
        float wi = Wi[i * 128 + o], wj = Wj[i * 128 + o];
#pragma unroll
        for (int k = 0; k < KN; ++k) {
            float hv = sH[(nl * KN + k) * 128 + i];
            gacc[k] += hv * wi;
            facc[k] += hv * wj;
        }
    }
    float bio = bi[o], bjo = bj[o];
    float psum = 0.f;
    int curg = sB[nl * KN];
#pragma unroll
    for (int k = 0; k < KN; ++k) {
        int r = nl * KN + k;
        int bg = sB[r];
        if (bg != curg) {
            atomicAdd(&pooled[curg * 128 + o], psum);
            psum = 0.f; curg = bg;
        }
        float gate = 1.f / (1.f + expf(-(gacc[k] + bio)));
        float feat = tanhf(facc[k] + bjo);
        psum += gate * feat;
    }
    atomicAdd(&pooled[curg * 128 + o], psum);
}

// ---------------- final: tanh(pooled) @ Wfc + bfc, split halves ----------------
__global__ __launch_bounds__(256) void k_final(
    const float* __restrict__ pooled, const float* __restrict__ Wfc,
    const float* __restrict__ bfc, float* __restrict__ out)
{
    __shared__ float sP[128];
    const int g = blockIdx.x, c = threadIdx.x;
    if (c < 128) sP[c] = tanhf(pooled[g * 128 + c]);
    __syncthreads();
    float z = bfc[c];
    for (int i = 0; i < 128; ++i) z += sP[i] * Wfc[i * 256 + c];
    int oidx = (c < 128) ? (g * 128 + c) : (NG * 128 + g * 128 + (c - 128));
    out[oidx] = z;
}

extern "C" void kernel_launch(void* const* d_in, const int* in_sizes, int n_in,
                              void* d_out, int out_size, void* d_ws, size_t ws_size,
                              hipStream_t stream)
{
    (void)in_sizes; (void)n_in; (void)out_size; (void)ws_size;
    const float* x     = (const float*)d_in[0];
    const float* eattr = (const float*)d_in[1];
    const int*   ei    = (const int*)d_in[2];
    const int*   batch = (const int*)d_in[3];
    const float* We1 = (const float*)d_in[4];
    const float* be1 = (const float*)d_in[5];
    const float* bias1 = (const float*)d_in[6];
    const float* Wr1 = (const float*)d_in[7];
    const float* br1 = (const float*)d_in[8];
    const float* bg1 = (const float*)d_in[9];
    const float* bb1 = (const float*)d_in[10];
    const float* a1  = (const float*)d_in[11];
    const float* We2 = (const float*)d_in[12];
    const float* be2 = (const float*)d_in[13];
    const float* bias2 = (const float*)d_in[14];
    const float* Wr2 = (const float*)d_in[15];
    const float* br2 = (const float*)d_in[16];
    const float* bg2 = (const float*)d_in[17];
    const float* bb2 = (const float*)d_in[18];
    const float* a2  = (const float*)d_in[19];
    const float* We3 = (const float*)d_in[20];
    const float* be3 = (const float*)d_in[21];
    const float* bias3 = (const float*)d_in[22];
    const float* Wr3 = (const float*)d_in[23];
    const float* br3 = (const float*)d_in[24];
    const float* bg3 = (const float*)d_in[25];
    const float* bb3 = (const float*)d_in[26];
    const float* a3  = (const float*)d_in[27];
    const float* Wi  = (const float*)d_in[28];
    const float* bi  = (const float*)d_in[29];
    const float* Wj  = (const float*)d_in[30];
    const float* bj  = (const float*)d_in[31];
    const float* Wfc = (const float*)d_in[32];
    const float* bfc = (const float*)d_in[33];
    float* ws  = (float*)d_ws;
    float* out = (float*)d_out;

    hipMemsetAsync(d_ws, 0, (size_t)ZERO_FLOATS * sizeof(float), stream);

    // layer 1: K=16, COUT=32 (no BN on x); deg-count blocks merged into proj1 launch
    k_proj<16, 32, false, true><<<64 * 5 + 64, 256, 0, stream>>>(
        x, We1, be1, Wr1, bias1, br1, ei, ws + OFF_DEG,
        ws + OFF_Y, ws + OFF_H1, nullptr, nullptr, nullptr, nullptr);
    k_egather<32><<<NE * 8 / 256, 256, 0, stream>>>(
        ws + OFF_Y, eattr, ei, ws + OFF_DEG, ws + OFF_H1);
    k_stats<32><<<NN / 16, 256, 0, stream>>>(ws + OFF_H1, ws + OFF_ST1);

    // layer 2: K=32, COUT=64 (BN1 folded into A load)
    k_proj<32, 64, true, false><<<64 * 10, 256, 0, stream>>>(
        ws + OFF_H1, We2, be2, Wr2, bias2, br2, nullptr, nullptr,
        ws + OFF_Y, ws + OFF_H2, ws + OFF_ST1, bg1, bb1, a1);
    k_egather<64><<<NE * 16 / 256, 256, 0, stream>>>(
        ws + OFF_Y, eattr, ei, ws + OFF_DEG, ws + OFF_H2);
    k_stats<64><<<NN / 16, 256, 0, stream>>>(ws + OFF_H2, ws + OFF_ST2);

    // layer 3: K=64, COUT=128 (BN2 folded)
    k_proj<64, 128, true, false><<<64 * 20, 256, 0, stream>>>(
        ws + OFF_H2, We3, be3, Wr3, bias3, br3, nullptr, nullptr,
        ws + OFF_Y, ws + OFF_H3, ws + OFF_ST2, bg2, bb2, a2);
    k_egather<128><<<NE * 32 / 256, 256, 0, stream>>>(
        ws + OFF_Y, eattr, ei, ws + OFF_DEG, ws + OFF_H3);
    k_stats<128><<<NN / 16, 256, 0, stream>>>(ws + OFF_H3, ws + OFF_ST3);

    // pooling (BN3 folded, run-aggregated atomics) + head
    k_pool<<<NN / 16, 256, 0, stream>>>(ws + OFF_H3, batch, Wi, bi, Wj, bj, ws + OFF_POOL,
                                        ws + OFF_ST3, bg3, bb3, a3);
    k_final<<<NG, 256, 0, stream>>>(ws + OFF_POOL, Wfc, bfc, out);
}

// Round 9
// 239.451 us; speedup vs baseline: 2.9619x; 1.1576x over previous
//
#include <hip/hip_runtime.h>
#include <math.h>

#define NN 4096
#define NE 16384
#define NG 64

// ---- ws layout (float offsets); zero region first (~51KB memset) ----
#define OFF_DEG   0         // 4096
#define OFF_ST1   4096      // 64
#define OFF_ST2   4160      // 128
#define OFF_ST3   4288      // 256
#define OFF_POOL  4544      // 64*128 = 8192
#define ZERO_FLOATS 12736
#define OFF_H1    12736     // 4096*32
#define OFF_H2    143808    // 4096*64
#define OFF_H3    405952    // 4096*128
#define OFF_Y     930240    // 4096*1152 max (reused across layers)

// ---------------- proj: Y[n,col]=sum_i bnp(A[n,i])*Bcat[i,col]; resid cols -> h-init ----------------
// Bcat built on the fly from We/be/Wr (no materialization):
//   col = f*COUT + o;  f<8 -> We[f*K*COUT + o*K + i];  f==8 -> be[o*K+i];  f==9 -> Wr[i*COUT+o]
// cols < 9*COUT -> Y (unnormalized; norm applied in egather)
// cols >= 9*COUT -> h[m*COUT+o] = acc + bias[o] + br[o]   (residual init, written once)
// DEG=true: trailing 64 blocks count src out-degree (independent work, merged launch).
template<int K, int COUT, bool BN, bool DEG>
__global__ __launch_bounds__(256) void k_proj(
    const float* __restrict__ A,
    const float* __restrict__ We, const float* __restrict__ be,
    const float* __restrict__ Wr, const float* __restrict__ bias,
    const float* __restrict__ br,
    const int* __restrict__ ei, float* __restrict__ deg,
    float* __restrict__ Y, float* __restrict__ h,
    const float* __restrict__ st, const float* __restrict__ g,
    const float* __restrict__ b, const float* __restrict__ a)
{
    constexpr int NCOL = 10 * COUT;
    constexpr int NY = NCOL / 64;       // exact: 5 / 10 / 20
    constexpr int NC9 = 9 * COUT;
    constexpr int L2C = (COUT == 32) ? 5 : (COUT == 64) ? 6 : 7;

    const int tid = threadIdx.x;
    const int bid = blockIdx.x;

    if constexpr (DEG) {
        if (bid >= 64 * NY) {
            int e = (bid - 64 * NY) * 256 + tid;
            if (e < NE) atomicAdd(&deg[ei[e]], 1.0f);
            return;
        }
    }

    __shared__ float sA[K][68];
    __shared__ float sB[K][68];
    __shared__ float sS[K];
    __shared__ float sT[K];
    const int m0 = (bid & 63) * 64;
    const int n0 = (bid >> 6) * 64;

    float al = 0.f;
    if constexpr (BN) {
        if (tid < K) {
            float mean = st[tid] * (1.f / NN);
            float var  = st[K + tid] * (1.f / NN) - mean * mean;
            var = fmaxf(var, 0.f);
            float s = rsqrtf(var + 1e-5f) * g[tid];
            sS[tid] = s;
            sT[tid] = b[tid] - mean * s;
        }
        al = a[0];
        __syncthreads();
    }

    for (int t = tid; t < 64 * K; t += 256) {
        int m = t / K, i = t - m * K;
        float v = A[(m0 + m) * K + i];
        if constexpr (BN) {
            v = fmaf(v, sS[i], sT[i]);
            v = v >= 0.f ? v : al * v;
        }
        sA[i][m] = v;
    }
    for (int t = tid; t < 64 * K; t += 256) {
        int i = t >> 6, n = t & 63;
        int col = n0 + n;
        int f = col >> L2C;
        int o = col & (COUT - 1);
        float v;
        if (f < 8)       v = We[f * K * COUT + o * K + i];
        else if (f == 8) v = be[o * K + i];
        else             v = Wr[i * COUT + o];
        sB[i][n] = v;
    }
    __syncthreads();

    const int tn = tid & 15, tm = tid >> 4;
    float acc[4][4] = {{0.f}};
#pragma unroll 8
    for (int i = 0; i < K; ++i) {
        float4 av = *(const float4*)&sA[i][tm * 4];
        float4 bv = *(const float4*)&sB[i][tn * 4];
        acc[0][0] += av.x * bv.x; acc[0][1] += av.x * bv.y; acc[0][2] += av.x * bv.z; acc[0][3] += av.x * bv.w;
        acc[1][0] += av.y * bv.x; acc[1][1] += av.y * bv.y; acc[1][2] += av.y * bv.z; acc[1][3] += av.y * bv.w;
        acc[2][0] += av.z * bv.x; acc[2][1] += av.z * bv.y; acc[2][2] += av.z * bv.z; acc[2][3] += av.z * bv.w;
        acc[3][0] += av.w * bv.x; acc[3][1] += av.w * bv.y; acc[3][2] += av.w * bv.z; acc[3][3] += av.w * bv.w;
    }

#pragma unroll
    for (int mm = 0; mm < 4; ++mm) {
        int m = m0 + tm * 4 + mm;
#pragma unroll
        for (int nn = 0; nn < 4; ++nn) {
            int col = n0 + tn * 4 + nn;
            if (col < NC9) {
                Y[(size_t)m * NC9 + col] = acc[mm][nn];
            } else {
                int o = col - NC9;
                h[m * COUT + o] = acc[mm][nn] + bias[o] + br[o];
            }
        }
    }
}

// ---------------- egather: h[dst,o] += (1/deg[src]) * (sum_f ea[f]*Y[src,f*COUT+o] + Y[src,8*COUT+o]) ----------------
template<int COUT>
__global__ __launch_bounds__(256) void k_egather(
    const float* __restrict__ Y, const float* __restrict__ eattr,
    const int* __restrict__ ei, const float* __restrict__ deg,
    float* __restrict__ h)
{
    int idx = blockIdx.x * 256 + threadIdx.x;
    int e = idx / COUT;
    int o = idx - e * COUT;
    int src = ei[e], dst = ei[NE + e];
    float d = deg[src];
    float nrm = d > 0.f ? 1.f / d : 0.f;
    const float* y = Y + (size_t)src * (9 * COUT);
    const float* ea = eattr + e * 8;
    float acc = y[8 * COUT + o];      // be-term, ea' = 1
#pragma unroll
    for (int f = 0; f < 8; ++f) acc += ea[f] * y[f * COUT + o];
    atomicAdd(&h[dst * COUT + o], nrm * acc);
}

// ---------------- stats: per-channel sum/sumsq of h -> st ----------------
template<int COUT>
__global__ __launch_bounds__(256) void k_stats(
    const float* __restrict__ h, float* __restrict__ st)
{
    constexpr int NL = 256 / COUT;
    constexpr int KN = 16 / NL;
    __shared__ float sred[256];
    const int tid = threadIdx.x;
    const int nbase = blockIdx.x * 16;
    const int o = tid % COUT;
    const int nl = tid / COUT;

    float sum = 0.f, sumsq = 0.f;
#pragma unroll
    for (int k = 0; k < KN; ++k) {
        int r = nl * KN + k;
        float v = h[(nbase + r) * COUT + o];
        sum += v; sumsq += v * v;
    }
    sred[tid] = sum;
    __syncthreads();
    if (tid < COUT) {
        float s = 0.f;
        for (int q = 0; q < NL; ++q) s += sred[q * COUT + tid];
        atomicAdd(&st[tid], s);
    }
    __syncthreads();
    sred[tid] = sumsq;
    __syncthreads();
    if (tid < COUT) {
        float s = 0.f;
        for (int q = 0; q < NL; ++q) s += sred[q * COUT + tid];
        atomicAdd(&st[COUT + tid], s);
    }
}

// ---------------- pool: BN3+PReLU3 on load, gated attention, run-aggregated atomics ----------------
__global__ __launch_bounds__(256) void k_pool(
    const float* __restrict__ h3, const int* __restrict__ batch,
    const float* __restrict__ Wi, const float* __restrict__ bi,
    const float* __restrict__ Wj, const float* __restrict__ bj,
    float* __restrict__ pooled,
    const float* __restrict__ st, const float* __restrict__ g,
    const float* __restrict__ b, const float* __restrict__ a)
{
    constexpr int KN = 8, NB = 16;
    __shared__ float sH[NB * 128];
    __shared__ int sB[NB];
    __shared__ float sS[128];
    __shared__ float sT[128];
    const int tid = threadIdx.x;
    const int nbase = blockIdx.x * NB;

    if (tid < 128) {
        float mean = st[tid] * (1.f / NN);
        float var  = st[128 + tid] * (1.f / NN) - mean * mean;
        var = fmaxf(var, 0.f);
        float s = rsqrtf(var + 1e-5f) * g[tid];
        sS[tid] = s;
        sT[tid] = b[tid] - mean * s;
    }
    if (tid < NB) sB[tid] = batch[nbase + tid];
    __syncthreads();
    const float al = a[0];

    for (int t = tid; t < NB * 128; t += 256) {
        int c = t & 127;
        float v = h3[nbase * 128 + t];
        v = fmaf(v, sS[c], sT[c]);
        v = v >= 0.f ? v : al * v;
        sH[t] = v;
    }
    __syncthreads();

    const int o = tid & 127, nl = tid >> 7;
    float gacc[KN], facc[KN];
#pragma unroll
    for (int k = 0; k < KN; ++k) { gacc[k] = 0.f; facc[k] = 0.f; }
    for (int i = 0; i < 128; ++i) {
        float wi = Wi[i * 128 + o], wj = Wj[i * 128 + o];
#pragma unroll
        for (int k = 0; k < KN; ++k) {
            float hv = sH[(nl * KN + k) * 128 + i];
            gacc[k] += hv * wi;
            facc[k] += hv * wj;
        }
    }
    float bio = bi[o], bjo = bj[o];
    float psum = 0.f;
    int curg = sB[nl * KN];
#pragma unroll
    for (int k = 0; k < KN; ++k) {
        int r = nl * KN + k;
        int bg = sB[r];
        if (bg != curg) {
            atomicAdd(&pooled[curg * 128 + o], psum);
            psum = 0.f; curg = bg;
        }
        float gate = 1.f / (1.f + expf(-(gacc[k] + bio)));
        float feat = tanhf(facc[k] + bjo);
        psum += gate * feat;
    }
    atomicAdd(&pooled[curg * 128 + o], psum);
}

// ---------------- final: tanh(pooled) @ Wfc + bfc, split halves ----------------
__global__ __launch_bounds__(256) void k_final(
    const float* __restrict__ pooled, const float* __restrict__ Wfc,
    const float* __restrict__ bfc, float* __restrict__ out)
{
    __shared__ float sP[128];
    const int g = blockIdx.x, c = threadIdx.x;
    if (c < 128) sP[c] = tanhf(pooled[g * 128 + c]);
    __syncthreads();
    float z = bfc[c];
    for (int i = 0; i < 128; ++i) z += sP[i] * Wfc[i * 256 + c];
    int oidx = (c < 128) ? (g * 128 + c) : (NG * 128 + g * 128 + (c - 128));
    out[oidx] = z;
}

extern "C" void kernel_launch(void* const* d_in, const int* in_sizes, int n_in,
                              void* d_out, int out_size, void* d_ws, size_t ws_size,
                              hipStream_t stream)
{
    (void)in_sizes; (void)n_in; (void)out_size; (void)ws_size;
    const float* x     = (const float*)d_in[0];
    const float* eattr = (const float*)d_in[1];
    const int*   ei    = (const int*)d_in[2];
    const int*   batch = (const int*)d_in[3];
    const float* We1 = (const float*)d_in[4];
    const float* be1 = (const float*)d_in[5];
    const float* bias1 = (const float*)d_in[6];
    const float* Wr1 = (const float*)d_in[7];
    const float* br1 = (const float*)d_in[8];
    const float* bg1 = (const float*)d_in[9];
    const float* bb1 = (const float*)d_in[10];
    const float* a1  = (const float*)d_in[11];
    const float* We2 = (const float*)d_in[12];
    const float* be2 = (const float*)d_in[13];
    const float* bias2 = (const float*)d_in[14];
    const float* Wr2 = (const float*)d_in[15];
    const float* br2 = (const float*)d_in[16];
    const float* bg2 = (const float*)d_in[17];
    const float* bb2 = (const float*)d_in[18];
    const float* a2  = (const float*)d_in[19];
    const float* We3 = (const float*)d_in[20];
    const float* be3 = (const float*)d_in[21];
    const float* bias3 = (const float*)d_in[22];
    const float* Wr3 = (const float*)d_in[23];
    const float* br3 = (const float*)d_in[24];
    const float* bg3 = (const float*)d_in[25];
    const float* bb3 = (const float*)d_in[26];
    const float* a3  = (const float*)d_in[27];
    const float* Wi  = (const float*)d_in[28];
    const float* bi  = (const float*)d_in[29];
    const float* Wj  = (const float*)d_in[30];
    const float* bj  = (const float*)d_in[31];
    const float* Wfc = (const float*)d_in[32];
    const float* bfc = (const float*)d_in[33];
    float* ws  = (float*)d_ws;
    float* out = (float*)d_out;

    hipMemsetAsync(d_ws, 0, (size_t)ZERO_FLOATS * sizeof(float), stream);

    // layer 1: K=16, COUT=32 (no BN on x); deg-count blocks merged into proj1 launch
    k_proj<16, 32, false, true><<<64 * 5 + 64, 256, 0, stream>>>(
        x, We1, be1, Wr1, bias1, br1, ei, ws + OFF_DEG,
        ws + OFF_Y, ws + OFF_H1, nullptr, nullptr, nullptr, nullptr);
    k_egather<32><<<NE * 32 / 256, 256, 0, stream>>>(
        ws + OFF_Y, eattr, ei, ws + OFF_DEG, ws + OFF_H1);
    k_stats<32><<<NN / 16, 256, 0, stream>>>(ws + OFF_H1, ws + OFF_ST1);

    // layer 2: K=32, COUT=64 (BN1 folded into A load)
    k_proj<32, 64, true, false><<<64 * 10, 256, 0, stream>>>(
        ws + OFF_H1, We2, be2, Wr2, bias2, br2, nullptr, nullptr,
        ws + OFF_Y, ws + OFF_H2, ws + OFF_ST1, bg1, bb1, a1);
    k_egather<64><<<NE * 64 / 256, 256, 0, stream>>>(
        ws + OFF_Y, eattr, ei, ws + OFF_DEG, ws + OFF_H2);
    k_stats<64><<<NN / 16, 256, 0, stream>>>(ws + OFF_H2, ws + OFF_ST2);

    // layer 3: K=64, COUT=128 (BN2 folded)
    k_proj<64, 128, true, false><<<64 * 20, 256, 0, stream>>>(
        ws + OFF_H2, We3, be3, Wr3, bias3, br3, nullptr, nullptr,
        ws + OFF_Y, ws + OFF_H3, ws + OFF_ST2, bg2, bb2, a2);
    k_egather<128><<<NE * 128 / 256, 256, 0, stream>>>(
        ws + OFF_Y, eattr, ei, ws + OFF_DEG, ws + OFF_H3);
    k_stats<128><<<NN / 16, 256, 0, stream>>>(ws + OFF_H3, ws + OFF_ST3);

    // pooling (BN3 folded, run-aggregated atomics) + head
    k_pool<<<NN / 16, 256, 0, stream>>>(ws + OFF_H3, batch, Wi, bi, Wj, bj, ws + OFF_POOL,
                                        ws + OFF_ST3, bg3, bb3, a3);
    k_final<<<NG, 256, 0, stream>>>(ws + OFF_POOL, Wfc, bfc, out);
}